// Round 4
// baseline (198.560 us; speedup 1.0000x reference)
//
#include <hip/hip_runtime.h>
#include <stdint.h>

// Problem constants
#define Bb 2
#define Tt 2048
#define DMm 1024
#define Hh 16
#define HDd 64
#define Mrows (Bb*Tt)          // 4096

typedef __attribute__((ext_vector_type(8)))  __bf16 bf16x8;
typedef __attribute__((ext_vector_type(4)))  __bf16 bf16x4;
typedef __attribute__((ext_vector_type(4)))  float  f32x4;
typedef __attribute__((ext_vector_type(16))) float  f32x16;
typedef __attribute__((ext_vector_type(4)))  unsigned int u32x4;
typedef __attribute__((ext_vector_type(2)))  unsigned int u32x2;

#define GLD16(gp, lp) __builtin_amdgcn_global_load_lds( \
    (const __attribute__((address_space(1))) unsigned int*)(gp), \
    (__attribute__((address_space(3))) unsigned int*)(lp), 16, 0, 0)

static __device__ __forceinline__ unsigned cvtpk_bf16(float lo, float hi) {
  unsigned r;
  asm("v_cvt_pk_bf16_f32 %0, %1, %2" : "=v"(r) : "v"(lo), "v"(hi));
  return r;
}
static __device__ __forceinline__ float exp2_hw(float x) {
  float r;
  asm("v_exp_f32 %0, %1" : "=v"(r) : "v"(x));
  return r;
}

// ---------------- cast fp32 -> bf16 (vectorized) ----------------
__global__ __launch_bounds__(256)
void cast_k(const float* __restrict__ in, __bf16* __restrict__ out, int n4) {
  int i = blockIdx.x * 256 + threadIdx.x;
  if (i >= n4) return;
  float4 v = ((const float4*)in)[i];
  bf16x4 o;
  o[0] = (__bf16)v.x; o[1] = (__bf16)v.y; o[2] = (__bf16)v.z; o[3] = (__bf16)v.w;
  ((bf16x4*)out)[i] = o;
}

// ---------------- GEMM: C[M][N] = A[M][K] * B[N][K]^T ----------------------
// 128x128 tile, BK=32, 256 threads = 4 waves (2x2), each wave 64x64 (4x4 frags)
// Two variants: fp32 output and bf16 output.
#define GEMM_BODY(CSTORE)                                                     \
  __shared__ __bf16 As[128 * 32];                                             \
  __shared__ __bf16 Bs[128 * 32];                                             \
  const int tid  = threadIdx.x;                                               \
  const int lane = tid & 63, wid = tid >> 6;                                  \
  const int l4 = lane & 15, lhi = lane >> 4;                                  \
  const int rowBase = blockIdx.y * 128, colBase = blockIdx.x * 128;           \
  const int wh = wid >> 1, ww = wid & 1;                                      \
  f32x4 acc[4][4] = {};                                                       \
  const int e0 = wid * 512 + lane * 8;                                        \
  const int r0 = e0 >> 5, c0 = e0 & 31;                                       \
  const __bf16* a0 = A  + (size_t)(rowBase + r0)      * K + c0;               \
  const __bf16* a1 = A  + (size_t)(rowBase + r0 + 64) * K + c0;               \
  const __bf16* b0 = Bm + (size_t)(colBase + r0)      * K + c0;               \
  const __bf16* b1 = Bm + (size_t)(colBase + r0 + 64) * K + c0;               \
  for (int k0 = 0; k0 < K; k0 += 32) {                                        \
    __syncthreads();                                                          \
    GLD16(a0 + k0, &As[wid * 512]);                                           \
    GLD16(a1 + k0, &As[2048 + wid * 512]);                                    \
    GLD16(b0 + k0, &Bs[wid * 512]);                                           \
    GLD16(b1 + k0, &Bs[2048 + wid * 512]);                                    \
    __syncthreads();                                                          \
    bf16x8 af[4], bfr[4];                                                     \
    _Pragma("unroll")                                                         \
    for (int i = 0; i < 4; i++) {                                             \
      af[i]  = *(const bf16x8*)&As[(wh * 64 + i * 16 + l4) * 32 + lhi * 8];   \
      bfr[i] = *(const bf16x8*)&Bs[(ww * 64 + i * 16 + l4) * 32 + lhi * 8];   \
    }                                                                         \
    _Pragma("unroll")                                                         \
    for (int i = 0; i < 4; i++)                                               \
      _Pragma("unroll")                                                       \
      for (int j = 0; j < 4; j++)                                             \
        acc[i][j] = __builtin_amdgcn_mfma_f32_16x16x32_bf16(af[i], bfr[j], acc[i][j], 0, 0, 0); \
  }                                                                           \
  _Pragma("unroll")                                                           \
  for (int i = 0; i < 4; i++) {                                               \
    int R = rowBase + wh * 64 + i * 16 + lhi * 4;                             \
    _Pragma("unroll")                                                         \
    for (int j = 0; j < 4; j++) {                                             \
      int Cc = colBase + ww * 64 + j * 16 + l4;                               \
      CSTORE;                                                                 \
    }                                                                         \
  }

__global__ __launch_bounds__(256)
void gemm_bt(const __bf16* __restrict__ A, const __bf16* __restrict__ Bm,
             float* __restrict__ C, int M, int N, int K) {
  GEMM_BODY({
    float* cp = C + (size_t)R * N + Cc;
    _Pragma("unroll")
    for (int q = 0; q < 4; q++) cp[(size_t)q * N] = acc[i][j][q];
  })
}

__global__ __launch_bounds__(256)
void gemm_bt_h(const __bf16* __restrict__ A, const __bf16* __restrict__ Bm,
               __bf16* __restrict__ C, int M, int N, int K) {
  GEMM_BODY({
    __bf16* cp = C + (size_t)R * N + Cc;
    _Pragma("unroll")
    for (int q = 0; q < 4; q++) cp[(size_t)q * N] = (__bf16)acc[i][j][q];
  })
}

// ---------------- RoPE (bf16 in) + scatter Q/K [B,H,T,64], V^T [B,H,64,T] ---
// Q gets 0.125 * log2(e) folded in (softmax scale + exp2 domain).
__global__ __launch_bounds__(256)
void rope_k(const __bf16* __restrict__ qkv, const float* __restrict__ cosb,
            const float* __restrict__ sinb,
            __bf16* __restrict__ Q, __bf16* __restrict__ K, __bf16* __restrict__ Vt) {
  const int bh = blockIdx.y;           // b*16 + h
  const int b = bh >> 4, h = bh & 15;
  const int t0 = blockIdx.x * 64;
  __shared__ float Vl[64][65];
  const int tid = threadIdx.x;
  const int d = tid & 63;
  const int tl0 = tid >> 6;

  for (int it = 0; it < 16; ++it) {
    int tl = it * 4 + tl0;
    int t = t0 + tl;
    const __bf16* row = qkv + (size_t)(b * Tt + t) * 3072 + h * 64;
    float q  = (float)row[d],        qp = (float)row[d ^ 32];
    float k  = (float)row[1024 + d], kp = (float)row[1024 + (d ^ 32)];
    float v  = (float)row[2048 + d];
    float c  = cosb[t * 64 + d], sn = sinb[t * 64 + d];
    float sg = (d < 32) ? -1.f : 1.f;
    float qr = q * c + sg * qp * sn;
    float kr = k * c + sg * kp * sn;
    size_t o = (size_t)bh * Tt * 64 + (size_t)t * 64 + d;
    Q[o] = (__bf16)(qr * 0.18033688f);   // 0.125 * log2(e)
    K[o] = (__bf16)kr;
    Vl[tl][d] = v;
  }
  __syncthreads();
  for (int it = 0; it < 16; ++it) {
    int dr = it * 4 + tl0;
    Vt[(size_t)bh * 64 * Tt + (size_t)dr * Tt + t0 + d] = (__bf16)Vl[d][dr];
  }
}

// ---------------- Flash attention, swapped QK^T, k-parity split -------------
// grid: 1024 blocks x 256 thr = 4 waves: (wq = q-subtile of 32 rows, wk = key
// tile parity). Wave (wq,wk) runs online softmax over k-tiles wk, wk+2, ...;
// the two parities merge via LDS at the end (flash-decoding combine).
// bid -> (bh, qt) permuted so 4 co-resident blocks per CU get complementary qt.
__global__ __launch_bounds__(256, 4)
void attn_k(const __bf16* __restrict__ Q, const __bf16* __restrict__ K,
            const __bf16* __restrict__ Vt, __bf16* __restrict__ O) {
  const int bid = blockIdx.x;
  const int bh = bid >> 5;
  const int x  = bid & 31;
  const int h4 = bh >> 3;                       // 0..3
  const int xx = (h4 & 2) ? ((x + 16) & 31) : x;
  const int qt = (h4 & 1) ? (31 - xx) : xx;     // per-CU: {x,31-x,x+16,15-x}
  const int b = bh >> 4, h = bh & 15;
  const int tid = threadIdx.x, lane = tid & 63, wid = tid >> 6;
  const int wq = wid >> 1, wk = wid & 1;
  const int l5 = lane & 31, hi = lane >> 5;
  const int qrow0 = qt * 64 + wq * 32;
  const size_t baseQK = (size_t)bh * Tt * 64;
  const size_t baseVt = (size_t)bh * 64 * Tt;
  const float NEG_INF = -__builtin_inff();

  __shared__ float oL[2][2][32][32];    // [wq][writer wk][q][d-in-half] 16KB
  __shared__ float msL[2][2][32][2];    // [wq][wk][q][(m,ssum)]

  // Q as B-operand: col q = l5, contraction d = c*16 + hi*8 + j
  bf16x8 qf[4];
#pragma unroll
  for (int c = 0; c < 4; c++)
    qf[c] = *(const bf16x8*)(Q + baseQK + (size_t)(qrow0 + l5) * 64 + c * 16 + hi * 8);

  f32x16 o0 = {}, o1 = {};
  float m = NEG_INF, ssum = 0.f;

  const __bf16* Kbase = K  + baseQK + (size_t)l5 * 64 + hi * 8;
  const __bf16* Vbase = Vt + baseVt + (size_t)l5 * Tt + hi * 8;

  const int NT = 2 * qt + wq + 1;          // causal tile count for this q-sub
  const int n  = (NT + 1 - wk) >> 1;       // tiles with parity wk

#define LOADT(K0,K1,K2,K3,V00,V01,V10,V11,KT) do {                        \
    const __bf16* Kp = Kbase + (size_t)(KT) * 64;                         \
    K0 = *(const bf16x8*)(Kp);      K1 = *(const bf16x8*)(Kp + 16);       \
    K2 = *(const bf16x8*)(Kp + 32); K3 = *(const bf16x8*)(Kp + 48);       \
    const __bf16* Vp = Vbase + (KT);                                      \
    V00 = *(const bf16x8*)(Vp);                                           \
    V01 = *(const bf16x8*)(Vp + 16);                                      \
    V10 = *(const bf16x8*)(Vp + (size_t)32 * Tt);                         \
    V11 = *(const bf16x8*)(Vp + (size_t)32 * Tt + 16);                    \
  } while (0)

#define COMPUTE(K0,K1,K2,K3,V00,V01,V10,V11,KT0) do {                     \
    f32x16 s = {};                                                        \
    s = __builtin_amdgcn_mfma_f32_32x32x16_bf16(K0, qf[0], s, 0, 0, 0);   \
    s = __builtin_amdgcn_mfma_f32_32x32x16_bf16(K1, qf[1], s, 0, 0, 0);   \
    s = __builtin_amdgcn_mfma_f32_32x32x16_bf16(K2, qf[2], s, 0, 0, 0);   \
    s = __builtin_amdgcn_mfma_f32_32x32x16_bf16(K3, qf[3], s, 0, 0, 0);   \
    float sv[16];                                                         \
    if ((KT0) == qrow0) {                                                 \
      _Pragma("unroll")                                                   \
      for (int r = 0; r < 16; r++) {                                      \
        int kof = (r & 3) + 8 * (r >> 2) + 4 * hi;                        \
        sv[r] = (kof <= l5) ? s[r] : NEG_INF;                             \
      }                                                                   \
    } else {                                                              \
      _Pragma("unroll")                                                   \
      for (int r = 0; r < 16; r++) sv[r] = s[r];                          \
    }                                                                     \
    float pmax = sv[0];                                                   \
    _Pragma("unroll")                                                     \
    for (int r = 1; r < 16; r++) pmax = fmaxf(pmax, sv[r]);               \
    pmax = fmaxf(pmax, __shfl_xor(pmax, 32));                             \
    if (__any(pmax > m + 11.5f)) {                                        \
      float mn = fmaxf(m, pmax);                                          \
      float al = exp2_hw(m - mn);                                         \
      m = mn;                                                             \
      ssum *= al;                                                         \
      float arow[16];                                                     \
      _Pragma("unroll")                                                   \
      for (int r = 0; r < 16; r++)                                        \
        arow[r] = __shfl(al, (r & 3) + 8 * (r >> 2) + 4 * hi);            \
      _Pragma("unroll")                                                   \
      for (int r = 0; r < 16; r++) { o0[r] *= arow[r]; o1[r] *= arow[r]; }\
    }                                                                     \
    float p[16], rsl = 0.f;                                               \
    _Pragma("unroll")                                                     \
    for (int r = 0; r < 16; r++) { p[r] = exp2_hw(sv[r] - m); rsl += p[r]; } \
    ssum += rsl + __shfl_xor(rsl, 32);                                    \
    bf16x8 pa[2];                                                         \
    _Pragma("unroll")                                                     \
    for (int kc = 0; kc < 2; kc++) {                                      \
      const float* pp = p + kc * 8;                                       \
      unsigned X0 = cvtpk_bf16(pp[0], pp[1]);                             \
      unsigned Y0 = cvtpk_bf16(pp[4], pp[5]);                             \
      unsigned X1 = cvtpk_bf16(pp[2], pp[3]);                             \
      unsigned Y1 = cvtpk_bf16(pp[6], pp[7]);                             \
      u32x2 rr0 = __builtin_amdgcn_permlane32_swap(X0, Y0, false, false); \
      u32x2 rr1 = __builtin_amdgcn_permlane32_swap(X1, Y1, false, false); \
      u32x4 pw;                                                           \
      pw[0] = rr0[0]; pw[1] = rr1[0]; pw[2] = rr0[1]; pw[3] = rr1[1];     \
      pa[kc] = __builtin_bit_cast(bf16x8, pw);                            \
    }                                                                     \
    o0 = __builtin_amdgcn_mfma_f32_32x32x16_bf16(pa[0], V00, o0, 0, 0, 0);\
    o0 = __builtin_amdgcn_mfma_f32_32x32x16_bf16(pa[1], V01, o0, 0, 0, 0);\
    o1 = __builtin_amdgcn_mfma_f32_32x32x16_bf16(pa[0], V10, o1, 0, 0, 0);\
    o1 = __builtin_amdgcn_mfma_f32_32x32x16_bf16(pa[1], V11, o1, 0, 0, 0);\
  } while (0)

  bf16x8 kA0, kA1, kA2, kA3, vA00, vA01, vA10, vA11;
  bf16x8 kB0, kB1, kB2, kB3, vB00, vB01, vB10, vB11;

  // clamped tile start for load j (harmless re-read of tile qrow0 when OOB)
#define KTL(j) ( ((wk + 2 * (j)) * 32 > qrow0) ? qrow0 : (wk + 2 * (j)) * 32 )

  LOADT(kA0,kA1,kA2,kA3,vA00,vA01,vA10,vA11, KTL(0));
  int i = 0;
  for (; i + 2 <= n; i += 2) {
    LOADT(kB0,kB1,kB2,kB3,vB00,vB01,vB10,vB11, KTL(i + 1));
    COMPUTE(kA0,kA1,kA2,kA3,vA00,vA01,vA10,vA11, (wk + 2 * i) * 32);
    LOADT(kA0,kA1,kA2,kA3,vA00,vA01,vA10,vA11, KTL(i + 2));
    COMPUTE(kB0,kB1,kB2,kB3,vB00,vB01,vB10,vB11, (wk + 2 * (i + 1)) * 32);
  }
  if (i < n)
    COMPUTE(kA0,kA1,kA2,kA3,vA00,vA01,vA10,vA11, (wk + 2 * i) * 32);

  // ---- flash-decoding combine across the two k-parities ----
  // wave wk merges d-half wk; writes the OTHER half for its partner.
  if (wk == 0) {
#pragma unroll
    for (int r = 0; r < 16; r++) {
      int row = (r & 3) + 8 * (r >> 2) + 4 * hi;
      oL[wq][0][row][l5] = o1[r];
    }
  } else {
#pragma unroll
    for (int r = 0; r < 16; r++) {
      int row = (r & 3) + 8 * (r >> 2) + 4 * hi;
      oL[wq][1][row][l5] = o0[r];
    }
  }
  if (hi == 0) { msL[wq][wk][l5][0] = m; msL[wq][wk][l5][1] = ssum; }
  __syncthreads();

#pragma unroll
  for (int r = 0; r < 16; r++) {
    int row = (r & 3) + 8 * (r >> 2) + 4 * hi;
    float2 mo = *(const float2*)&msL[wq][wk][row][0];
    float2 mp = *(const float2*)&msL[wq][wk ^ 1][row][0];
    float mM = fmaxf(mo.x, mp.x);
    float aO = exp2_hw(mo.x - mM);
    float aP = exp2_hw(mp.x - mM);
    float inv = 1.f / (aO * mo.y + aP * mp.y);
    float op  = oL[wq][wk ^ 1][row][l5];
    float own = wk ? o1[r] : o0[r];
    float val = (aO * own + aP * op) * inv;
    int qg2 = qrow0 + row;
    O[((size_t)b * Tt + qg2) * DMm + h * 64 + wk * 32 + l5] = (__bf16)val;
  }
}

// ---------------- launch -----------------------------------------------------
extern "C" void kernel_launch(void* const* d_in, const int* in_sizes, int n_in,
                              void* d_out, int out_size, void* d_ws, size_t ws_size,
                              hipStream_t stream) {
  const float* x     = (const float*)d_in[0];
  const float* cosb  = (const float*)d_in[1];
  const float* sinb  = (const float*)d_in[2];
  const float* wqkv  = (const float*)d_in[3];
  const float* wproj = (const float*)d_in[4];
  float* out = (float*)d_out;

  char* ws = (char*)d_ws;
  __bf16* xb     = (__bf16*)(ws + 0);          //  8 MB  (4096x1024)
  __bf16* wqkvb  = (__bf16*)(ws + 8388608);    //  6 MB  (3072x1024)
  __bf16* wprojb = (__bf16*)(ws + 14680064);   //  2 MB  (1024x1024)
  __bf16* qkvh   = (__bf16*)(ws + 16777216);   // 24 MB  (4096x3072 bf16)
  __bf16* Qb     = (__bf16*)(ws + 41943040);   //  8 MB  [B,H,T,64]
  __bf16* Kb     = (__bf16*)(ws + 50331648);   //  8 MB  [B,H,T,64]
  __bf16* Vtb    = (__bf16*)(ws + 58720256);   //  8 MB  [B,H,64,T]
  __bf16* attno  = (__bf16*)(ws + 67108864);   //  8 MB  [B,T,1024]

  cast_k<<<4096, 256, 0, stream>>>(x,     xb,     1048576);
  cast_k<<<3072, 256, 0, stream>>>(wqkv,  wqkvb,   786432);
  cast_k<<<1024, 256, 0, stream>>>(wproj, wprojb,  262144);

  dim3 g1(3072 / 128, Mrows / 128);
  gemm_bt_h<<<g1, 256, 0, stream>>>(xb, wqkvb, qkvh, Mrows, 3072, 1024);

  dim3 gr(Tt / 64, Bb * Hh);
  rope_k<<<gr, 256, 0, stream>>>(qkvh, cosb, sinb, Qb, Kb, Vtb);

  attn_k<<<1024, 256, 0, stream>>>(Qb, Kb, Vtb, attno);

  dim3 g2(DMm / 128, Mrows / 128);
  gemm_bt<<<g2, 256, 0, stream>>>(attno, wprojb, out, Mrows, DMm, 1024);
}

// Round 6
// 164.787 us; speedup vs baseline: 1.2050x; 1.2050x over previous
//
#include <hip/hip_runtime.h>
#include <stdint.h>

// Problem constants
#define Bb 2
#define Tt 2048
#define DMm 1024
#define Hh 16
#define HDd 64
#define Mrows (Bb*Tt)          // 4096

typedef __attribute__((ext_vector_type(8)))  __bf16 bf16x8;
typedef __attribute__((ext_vector_type(4)))  __bf16 bf16x4;
typedef __attribute__((ext_vector_type(4)))  float  f32x4;
typedef __attribute__((ext_vector_type(16))) float  f32x16;
typedef __attribute__((ext_vector_type(4)))  unsigned int u32x4;
typedef __attribute__((ext_vector_type(2)))  unsigned int u32x2;

#define GLD16(gp, lp) __builtin_amdgcn_global_load_lds( \
    (const __attribute__((address_space(1))) unsigned int*)(gp), \
    (__attribute__((address_space(3))) unsigned int*)(lp), 16, 0, 0)

static __device__ __forceinline__ unsigned cvtpk_bf16(float lo, float hi) {
  unsigned r;
  asm("v_cvt_pk_bf16_f32 %0, %1, %2" : "=v"(r) : "v"(lo), "v"(hi));
  return r;
}
static __device__ __forceinline__ float exp2_hw(float x) {
  float r;
  asm("v_exp_f32 %0, %1" : "=v"(r) : "v"(x));
  return r;
}
// cross-half reduce: validated __shfl_xor form (R3/R4).
// NOTE: permlane32_swap(u,u) with IDENTICAL operands mis-executed (R5 fail) —
// the instruction has two tied read-write operands; only use it with distinct
// values (as in the P-pack below).
static __device__ __forceinline__ float xmax32(float v) {
  return fmaxf(v, __shfl_xor(v, 32));
}
static __device__ __forceinline__ float xsum32(float v) {
  return v + __shfl_xor(v, 32);
}

// ---------------- cast fp32 -> bf16 (vectorized) ----------------
__global__ __launch_bounds__(256)
void cast_k(const float* __restrict__ in, __bf16* __restrict__ out, int n4) {
  int i = blockIdx.x * 256 + threadIdx.x;
  if (i >= n4) return;
  float4 v = ((const float4*)in)[i];
  bf16x4 o;
  o[0] = (__bf16)v.x; o[1] = (__bf16)v.y; o[2] = (__bf16)v.z; o[3] = (__bf16)v.w;
  ((bf16x4*)out)[i] = o;
}

// ---------------- GEMM: C[M][N] = A[M][K] * B[N][K]^T ----------------------
#define GEMM_BODY(CSTORE)                                                     \
  __shared__ __bf16 As[128 * 32];                                             \
  __shared__ __bf16 Bs[128 * 32];                                             \
  const int tid  = threadIdx.x;                                               \
  const int lane = tid & 63, wid = tid >> 6;                                  \
  const int l4 = lane & 15, lhi = lane >> 4;                                  \
  const int rowBase = blockIdx.y * 128, colBase = blockIdx.x * 128;           \
  const int wh = wid >> 1, ww = wid & 1;                                      \
  f32x4 acc[4][4] = {};                                                       \
  const int e0 = wid * 512 + lane * 8;                                        \
  const int r0 = e0 >> 5, c0 = e0 & 31;                                       \
  const __bf16* a0 = A  + (size_t)(rowBase + r0)      * K + c0;               \
  const __bf16* a1 = A  + (size_t)(rowBase + r0 + 64) * K + c0;               \
  const __bf16* b0 = Bm + (size_t)(colBase + r0)      * K + c0;               \
  const __bf16* b1 = Bm + (size_t)(colBase + r0 + 64) * K + c0;               \
  for (int k0 = 0; k0 < K; k0 += 32) {                                        \
    __syncthreads();                                                          \
    GLD16(a0 + k0, &As[wid * 512]);                                           \
    GLD16(a1 + k0, &As[2048 + wid * 512]);                                    \
    GLD16(b0 + k0, &Bs[wid * 512]);                                           \
    GLD16(b1 + k0, &Bs[2048 + wid * 512]);                                    \
    __syncthreads();                                                          \
    bf16x8 af[4], bfr[4];                                                     \
    _Pragma("unroll")                                                         \
    for (int i = 0; i < 4; i++) {                                             \
      af[i]  = *(const bf16x8*)&As[(wh * 64 + i * 16 + l4) * 32 + lhi * 8];   \
      bfr[i] = *(const bf16x8*)&Bs[(ww * 64 + i * 16 + l4) * 32 + lhi * 8];   \
    }                                                                         \
    _Pragma("unroll")                                                         \
    for (int i = 0; i < 4; i++)                                               \
      _Pragma("unroll")                                                       \
      for (int j = 0; j < 4; j++)                                             \
        acc[i][j] = __builtin_amdgcn_mfma_f32_16x16x32_bf16(af[i], bfr[j], acc[i][j], 0, 0, 0); \
  }                                                                           \
  _Pragma("unroll")                                                           \
  for (int i = 0; i < 4; i++) {                                               \
    int R = rowBase + wh * 64 + i * 16 + lhi * 4;                             \
    _Pragma("unroll")                                                         \
    for (int j = 0; j < 4; j++) {                                             \
      int Cc = colBase + ww * 64 + j * 16 + l4;                               \
      CSTORE;                                                                 \
    }                                                                         \
  }

__global__ __launch_bounds__(256)
void gemm_bt(const __bf16* __restrict__ A, const __bf16* __restrict__ Bm,
             float* __restrict__ C, int M, int N, int K) {
  GEMM_BODY({
    float* cp = C + (size_t)R * N + Cc;
    _Pragma("unroll")
    for (int q = 0; q < 4; q++) cp[(size_t)q * N] = acc[i][j][q];
  })
}

__global__ __launch_bounds__(256)
void gemm_bt_h(const __bf16* __restrict__ A, const __bf16* __restrict__ Bm,
               __bf16* __restrict__ C, int M, int N, int K) {
  GEMM_BODY({
    __bf16* cp = C + (size_t)R * N + Cc;
    _Pragma("unroll")
    for (int q = 0; q < 4; q++) cp[(size_t)q * N] = (__bf16)acc[i][j][q];
  })
}

// ---------------- RoPE (bf16 in) + scatter Q/K [B,H,T,64], V^T [B,H,64,T] ---
__global__ __launch_bounds__(256)
void rope_k(const __bf16* __restrict__ qkv, const float* __restrict__ cosb,
            const float* __restrict__ sinb,
            __bf16* __restrict__ Q, __bf16* __restrict__ K, __bf16* __restrict__ Vt) {
  const int bh = blockIdx.y;           // b*16 + h
  const int b = bh >> 4, h = bh & 15;
  const int t0 = blockIdx.x * 64;
  __shared__ float Vl[64][65];
  const int tid = threadIdx.x;
  const int d = tid & 63;
  const int tl0 = tid >> 6;

  for (int it = 0; it < 16; ++it) {
    int tl = it * 4 + tl0;
    int t = t0 + tl;
    const __bf16* row = qkv + (size_t)(b * Tt + t) * 3072 + h * 64;
    float q  = (float)row[d],        qp = (float)row[d ^ 32];
    float k  = (float)row[1024 + d], kp = (float)row[1024 + (d ^ 32)];
    float v  = (float)row[2048 + d];
    float c  = cosb[t * 64 + d], sn = sinb[t * 64 + d];
    float sg = (d < 32) ? -1.f : 1.f;
    float qr = q * c + sg * qp * sn;
    float kr = k * c + sg * kp * sn;
    size_t o = (size_t)bh * Tt * 64 + (size_t)t * 64 + d;
    Q[o] = (__bf16)(qr * 0.18033688f);   // 0.125 * log2(e)
    K[o] = (__bf16)kr;
    Vl[tl][d] = v;
  }
  __syncthreads();
  for (int it = 0; it < 16; ++it) {
    int dr = it * 4 + tl0;
    Vt[(size_t)bh * 64 * Tt + (size_t)dr * Tt + t0 + d] = (__bf16)Vl[d][dr];
  }
}

// ---------------- Flash attention, swapped QK^T, k-parity split -------------
// grid: 2048 blocks x 128 thr = 2 waves = the 2 k-tile parities of one 32-row
// q-subtile. Each wave: online softmax over its parity's tiles; LDS combine.
// bid -> (bh, qsub) so the 8 co-resident blocks per CU have constant total
// work: c=bid>>8, j=bid&7, qsub = c*8 + (c odd ? 7-j : j)  (sum 260/CU).
__global__ __launch_bounds__(128)
void attn_k(const __bf16* __restrict__ Q, const __bf16* __restrict__ K,
            const __bf16* __restrict__ Vt, __bf16* __restrict__ O) {
  const int bid = blockIdx.x;
  const int c8 = bid >> 8, rr8 = bid & 255;
  const int bh = rr8 >> 3, j8 = rr8 & 7;
  const int qsub = c8 * 8 + ((c8 & 1) ? 7 - j8 : j8);
  const int b = bh >> 4, h = bh & 15;
  const int tid = threadIdx.x, lane = tid & 63, wk = tid >> 6;
  const int l5 = lane & 31, hi = lane >> 5;
  const int qrow0 = qsub * 32;
  const size_t baseQK = (size_t)bh * Tt * 64;
  const size_t baseVt = (size_t)bh * 64 * Tt;
  const float NEG_INF = -__builtin_inff();

  __shared__ float oL[2][32][32];     // [writer wk][q-row][d-in-half]  8KB
  __shared__ float msL[2][32][2];     // [wk][q-row][(m,ssum)]

  // Q as B-operand: col q = l5, contraction d = cc*16 + hi*8 + elem
  bf16x8 qf[4];
#pragma unroll
  for (int cc = 0; cc < 4; cc++)
    qf[cc] = *(const bf16x8*)(Q + baseQK + (size_t)(qrow0 + l5) * 64 + cc * 16 + hi * 8);

  f32x16 o0 = {}, o1 = {};
  float m = NEG_INF, ssum = 0.f;

  const __bf16* Kbase = K  + baseQK + (size_t)l5 * 64 + hi * 8;
  const __bf16* Vbase = Vt + baseVt + (size_t)l5 * Tt + hi * 8;

  const int NT = qsub + 1;                 // causal 32-key tiles
  const int n  = (NT + 1 - wk) >> 1;       // tiles with parity wk

  bf16x8 kA[4], kB[4], vc[4];

#define LOADK(KA, KT) do {                                                \
    const __bf16* Kp = Kbase + (size_t)(KT) * 64;                         \
    KA[0] = *(const bf16x8*)(Kp);      KA[1] = *(const bf16x8*)(Kp + 16); \
    KA[2] = *(const bf16x8*)(Kp + 32); KA[3] = *(const bf16x8*)(Kp + 48); \
  } while (0)
#define LOADV(KT) do {                                                    \
    const __bf16* Vp = Vbase + (KT);                                      \
    vc[0] = *(const bf16x8*)(Vp);                                         \
    vc[1] = *(const bf16x8*)(Vp + 16);                                    \
    vc[2] = *(const bf16x8*)(Vp + (size_t)32 * Tt);                       \
    vc[3] = *(const bf16x8*)(Vp + (size_t)32 * Tt + 16);                  \
  } while (0)

#define COMPUTE(KA, KT0) do {                                             \
    f32x16 s = {};                                                        \
    s = __builtin_amdgcn_mfma_f32_32x32x16_bf16(KA[0], qf[0], s, 0, 0, 0);\
    s = __builtin_amdgcn_mfma_f32_32x32x16_bf16(KA[1], qf[1], s, 0, 0, 0);\
    s = __builtin_amdgcn_mfma_f32_32x32x16_bf16(KA[2], qf[2], s, 0, 0, 0);\
    s = __builtin_amdgcn_mfma_f32_32x32x16_bf16(KA[3], qf[3], s, 0, 0, 0);\
    float sv[16];                                                         \
    if ((KT0) == qrow0) {                                                 \
      _Pragma("unroll")                                                   \
      for (int r = 0; r < 16; r++) {                                      \
        int kof = (r & 3) + 8 * (r >> 2) + 4 * hi;                        \
        sv[r] = (kof <= l5) ? s[r] : NEG_INF;                             \
      }                                                                   \
    } else {                                                              \
      _Pragma("unroll")                                                   \
      for (int r = 0; r < 16; r++) sv[r] = s[r];                          \
    }                                                                     \
    float pmax = sv[0];                                                   \
    _Pragma("unroll")                                                     \
    for (int r = 1; r < 16; r++) pmax = fmaxf(pmax, sv[r]);               \
    pmax = xmax32(pmax);                                                  \
    if (__any(pmax > m + 11.5f)) {                                        \
      float mn = fmaxf(m, pmax);                                          \
      float al = exp2_hw(m - mn);                                         \
      m = mn;                                                             \
      ssum *= al;                                                         \
      float arow[16];                                                     \
      _Pragma("unroll")                                                   \
      for (int r = 0; r < 16; r++)                                        \
        arow[r] = __shfl(al, (r & 3) + 8 * (r >> 2) + 4 * hi);            \
      _Pragma("unroll")                                                   \
      for (int r = 0; r < 16; r++) { o0[r] *= arow[r]; o1[r] *= arow[r]; }\
    }                                                                     \
    float p[16], rsl = 0.f;                                               \
    _Pragma("unroll")                                                     \
    for (int r = 0; r < 16; r++) { p[r] = exp2_hw(sv[r] - m); rsl += p[r]; } \
    ssum += xsum32(rsl);                                                  \
    bf16x8 pa[2];                                                         \
    _Pragma("unroll")                                                     \
    for (int kc = 0; kc < 2; kc++) {                                      \
      const float* pp = p + kc * 8;                                       \
      unsigned X0 = cvtpk_bf16(pp[0], pp[1]);                             \
      unsigned Y0 = cvtpk_bf16(pp[4], pp[5]);                             \
      unsigned X1 = cvtpk_bf16(pp[2], pp[3]);                             \
      unsigned Y1 = cvtpk_bf16(pp[6], pp[7]);                             \
      u32x2 q0 = __builtin_amdgcn_permlane32_swap(X0, Y0, false, false);  \
      u32x2 q1 = __builtin_amdgcn_permlane32_swap(X1, Y1, false, false);  \
      u32x4 pw;                                                           \
      pw[0] = q0[0]; pw[1] = q1[0]; pw[2] = q0[1]; pw[3] = q1[1];         \
      pa[kc] = __builtin_bit_cast(bf16x8, pw);                            \
    }                                                                     \
    o0 = __builtin_amdgcn_mfma_f32_32x32x16_bf16(pa[0], vc[0], o0, 0, 0, 0);\
    o0 = __builtin_amdgcn_mfma_f32_32x32x16_bf16(pa[1], vc[1], o0, 0, 0, 0);\
    o1 = __builtin_amdgcn_mfma_f32_32x32x16_bf16(pa[0], vc[2], o1, 0, 0, 0);\
    o1 = __builtin_amdgcn_mfma_f32_32x32x16_bf16(pa[1], vc[3], o1, 0, 0, 0);\
  } while (0)

  // clamped tile start (harmless re-read of diagonal tile when overshooting)
#define KTC(idx) ( ((idx) * 32 > qrow0) ? qrow0 : (idx) * 32 )

  LOADK(kA, KTC(wk));
  int i = 0;
  for (; i + 2 <= n; i += 2) {
    LOADV((wk + 2 * i) * 32);
    LOADK(kB, KTC(wk + 2 * i + 2));
    COMPUTE(kA, (wk + 2 * i) * 32);
    LOADV((wk + 2 * i + 2) * 32);
    LOADK(kA, KTC(wk + 2 * i + 4));
    COMPUTE(kB, (wk + 2 * i + 2) * 32);
  }
  if (i < n) {
    LOADV((wk + 2 * i) * 32);
    COMPUTE(kA, (wk + 2 * i) * 32);
  }

  // ---- flash-decoding combine across the two k-parities ----
  // wave wk keeps d-half wk; writes the OTHER half to LDS for its partner.
  if (wk == 0) {
#pragma unroll
    for (int r = 0; r < 16; r++) {
      int row = (r & 3) + 8 * (r >> 2) + 4 * hi;
      oL[0][row][l5] = o1[r];
    }
  } else {
#pragma unroll
    for (int r = 0; r < 16; r++) {
      int row = (r & 3) + 8 * (r >> 2) + 4 * hi;
      oL[1][row][l5] = o0[r];
    }
  }
  if (hi == 0) { msL[wk][l5][0] = m; msL[wk][l5][1] = ssum; }
  __syncthreads();

#pragma unroll
  for (int r = 0; r < 16; r++) {
    int row = (r & 3) + 8 * (r >> 2) + 4 * hi;
    float2 mo = *(const float2*)&msL[wk][row][0];
    float2 mp = *(const float2*)&msL[wk ^ 1][row][0];
    float mM = fmaxf(mo.x, mp.x);
    float aO = exp2_hw(mo.x - mM);
    float aP = exp2_hw(mp.x - mM);
    float inv = 1.f / (aO * mo.y + aP * mp.y);
    float op  = oL[wk ^ 1][row][l5];
    float own = wk ? o1[r] : o0[r];
    float val = (aO * own + aP * op) * inv;
    int qg2 = qrow0 + row;
    O[((size_t)b * Tt + qg2) * DMm + h * 64 + wk * 32 + l5] = (__bf16)val;
  }
}

// ---------------- launch -----------------------------------------------------
extern "C" void kernel_launch(void* const* d_in, const int* in_sizes, int n_in,
                              void* d_out, int out_size, void* d_ws, size_t ws_size,
                              hipStream_t stream) {
  const float* x     = (const float*)d_in[0];
  const float* cosb  = (const float*)d_in[1];
  const float* sinb  = (const float*)d_in[2];
  const float* wqkv  = (const float*)d_in[3];
  const float* wproj = (const float*)d_in[4];
  float* out = (float*)d_out;

  char* ws = (char*)d_ws;
  __bf16* xb     = (__bf16*)(ws + 0);          //  8 MB  (4096x1024)
  __bf16* wqkvb  = (__bf16*)(ws + 8388608);    //  6 MB  (3072x1024)
  __bf16* wprojb = (__bf16*)(ws + 14680064);   //  2 MB  (1024x1024)
  __bf16* qkvh   = (__bf16*)(ws + 16777216);   // 24 MB  (4096x3072 bf16)
  __bf16* Qb     = (__bf16*)(ws + 41943040);   //  8 MB  [B,H,T,64]
  __bf16* Kb     = (__bf16*)(ws + 50331648);   //  8 MB  [B,H,T,64]
  __bf16* Vtb    = (__bf16*)(ws + 58720256);   //  8 MB  [B,H,64,T]
  __bf16* attno  = (__bf16*)(ws + 67108864);   //  8 MB  [B,T,1024]

  cast_k<<<4096, 256, 0, stream>>>(x,     xb,     1048576);
  cast_k<<<3072, 256, 0, stream>>>(wqkv,  wqkvb,   786432);
  cast_k<<<1024, 256, 0, stream>>>(wproj, wprojb,  262144);

  dim3 g1(3072 / 128, Mrows / 128);
  gemm_bt_h<<<g1, 256, 0, stream>>>(xb, wqkvb, qkvh, Mrows, 3072, 1024);

  dim3 gr(Tt / 64, Bb * Hh);
  rope_k<<<gr, 256, 0, stream>>>(qkvh, cosb, sinb, Qb, Kb, Vtb);

  attn_k<<<2048, 128, 0, stream>>>(Qb, Kb, Vtb, attno);

  dim3 g2(DMm / 128, Mrows / 128);
  gemm_bt<<<g2, 256, 0, stream>>>(attno, wprojb, out, Mrows, DMm, 1024);
}

// Round 7
// 159.022 us; speedup vs baseline: 1.2486x; 1.0363x over previous
//
#include <hip/hip_runtime.h>
#include <stdint.h>

// Problem constants
#define Bb 2
#define Tt 2048
#define DMm 1024
#define Hh 16
#define HDd 64
#define Mrows (Bb*Tt)          // 4096

typedef __attribute__((ext_vector_type(8)))  __bf16 bf16x8;
typedef __attribute__((ext_vector_type(4)))  __bf16 bf16x4;
typedef __attribute__((ext_vector_type(4)))  float  f32x4;
typedef __attribute__((ext_vector_type(16))) float  f32x16;
typedef __attribute__((ext_vector_type(4)))  unsigned int u32x4;
typedef __attribute__((ext_vector_type(2)))  unsigned int u32x2;

#define GLD16(gp, lp) __builtin_amdgcn_global_load_lds( \
    (const __attribute__((address_space(1))) unsigned int*)(gp), \
    (__attribute__((address_space(3))) unsigned int*)(lp), 16, 0, 0)

static __device__ __forceinline__ unsigned cvtpk_bf16(float lo, float hi) {
  unsigned r;
  asm("v_cvt_pk_bf16_f32 %0, %1, %2" : "=v"(r) : "v"(lo), "v"(hi));
  return r;
}
static __device__ __forceinline__ float exp2_hw(float x) {
  float r;
  asm("v_exp_f32 %0, %1" : "=v"(r) : "v"(x));
  return r;
}
// cross-half reduce: validated __shfl_xor form (R3/R4).
// NOTE: permlane32_swap(u,u) with IDENTICAL operands mis-executed (R5 fail) —
// only use it with distinct values (as in the P-pack below).
static __device__ __forceinline__ float xmax32(float v) {
  return fmaxf(v, __shfl_xor(v, 32));
}
static __device__ __forceinline__ float xsum32(float v) {
  return v + __shfl_xor(v, 32);
}

// ---------------- cast fp32 -> bf16 (vectorized) ----------------
__global__ __launch_bounds__(256)
void cast_k(const float* __restrict__ in, __bf16* __restrict__ out, int n4) {
  int i = blockIdx.x * 256 + threadIdx.x;
  if (i >= n4) return;
  float4 v = ((const float4*)in)[i];
  bf16x4 o;
  o[0] = (__bf16)v.x; o[1] = (__bf16)v.y; o[2] = (__bf16)v.z; o[3] = (__bf16)v.w;
  ((bf16x4*)out)[i] = o;
}

// ---------------- GEMM: C[M][N] = A[M][K] * B[N][K]^T ----------------------
#define GEMM_BODY(CSTORE)                                                     \
  __shared__ __bf16 As[128 * 32];                                             \
  __shared__ __bf16 Bs[128 * 32];                                             \
  const int tid  = threadIdx.x;                                               \
  const int lane = tid & 63, wid = tid >> 6;                                  \
  const int l4 = lane & 15, lhi = lane >> 4;                                  \
  const int rowBase = blockIdx.y * 128, colBase = blockIdx.x * 128;           \
  const int wh = wid >> 1, ww = wid & 1;                                      \
  f32x4 acc[4][4] = {};                                                       \
  const int e0 = wid * 512 + lane * 8;                                        \
  const int r0 = e0 >> 5, c0 = e0 & 31;                                       \
  const __bf16* a0 = A  + (size_t)(rowBase + r0)      * K + c0;               \
  const __bf16* a1 = A  + (size_t)(rowBase + r0 + 64) * K + c0;               \
  const __bf16* b0 = Bm + (size_t)(colBase + r0)      * K + c0;               \
  const __bf16* b1 = Bm + (size_t)(colBase + r0 + 64) * K + c0;               \
  for (int k0 = 0; k0 < K; k0 += 32) {                                        \
    __syncthreads();                                                          \
    GLD16(a0 + k0, &As[wid * 512]);                                           \
    GLD16(a1 + k0, &As[2048 + wid * 512]);                                    \
    GLD16(b0 + k0, &Bs[wid * 512]);                                           \
    GLD16(b1 + k0, &Bs[2048 + wid * 512]);                                    \
    __syncthreads();                                                          \
    bf16x8 af[4], bfr[4];                                                     \
    _Pragma("unroll")                                                         \
    for (int i = 0; i < 4; i++) {                                             \
      af[i]  = *(const bf16x8*)&As[(wh * 64 + i * 16 + l4) * 32 + lhi * 8];   \
      bfr[i] = *(const bf16x8*)&Bs[(ww * 64 + i * 16 + l4) * 32 + lhi * 8];   \
    }                                                                         \
    _Pragma("unroll")                                                         \
    for (int i = 0; i < 4; i++)                                               \
      _Pragma("unroll")                                                       \
      for (int j = 0; j < 4; j++)                                             \
        acc[i][j] = __builtin_amdgcn_mfma_f32_16x16x32_bf16(af[i], bfr[j], acc[i][j], 0, 0, 0); \
  }                                                                           \
  _Pragma("unroll")                                                           \
  for (int i = 0; i < 4; i++) {                                               \
    int R = rowBase + wh * 64 + i * 16 + lhi * 4;                             \
    _Pragma("unroll")                                                         \
    for (int j = 0; j < 4; j++) {                                             \
      int Cc = colBase + ww * 64 + j * 16 + l4;                               \
      CSTORE;                                                                 \
    }                                                                         \
  }

__global__ __launch_bounds__(256)
void gemm_bt(const __bf16* __restrict__ A, const __bf16* __restrict__ Bm,
             float* __restrict__ C, int M, int N, int K) {
  GEMM_BODY({
    float* cp = C + (size_t)R * N + Cc;
    _Pragma("unroll")
    for (int q = 0; q < 4; q++) cp[(size_t)q * N] = acc[i][j][q];
  })
}

__global__ __launch_bounds__(256)
void gemm_bt_h(const __bf16* __restrict__ A, const __bf16* __restrict__ Bm,
               __bf16* __restrict__ C, int M, int N, int K) {
  GEMM_BODY({
    __bf16* cp = C + (size_t)R * N + Cc;
    _Pragma("unroll")
    for (int q = 0; q < 4; q++) cp[(size_t)q * N] = (__bf16)acc[i][j][q];
  })
}

// ---------------- RoPE (bf16 in) + scatter Q/K [B,H,T,64], V^T [B,H,64,T] ---
__global__ __launch_bounds__(256)
void rope_k(const __bf16* __restrict__ qkv, const float* __restrict__ cosb,
            const float* __restrict__ sinb,
            __bf16* __restrict__ Q, __bf16* __restrict__ K, __bf16* __restrict__ Vt) {
  const int bh = blockIdx.y;           // b*16 + h
  const int b = bh >> 4, h = bh & 15;
  const int t0 = blockIdx.x * 64;
  __shared__ float Vl[64][65];
  const int tid = threadIdx.x;
  const int d = tid & 63;
  const int tl0 = tid >> 6;

  for (int it = 0; it < 16; ++it) {
    int tl = it * 4 + tl0;
    int t = t0 + tl;
    const __bf16* row = qkv + (size_t)(b * Tt + t) * 3072 + h * 64;
    float q  = (float)row[d],        qp = (float)row[d ^ 32];
    float k  = (float)row[1024 + d], kp = (float)row[1024 + (d ^ 32)];
    float v  = (float)row[2048 + d];
    float c  = cosb[t * 64 + d], sn = sinb[t * 64 + d];
    float sg = (d < 32) ? -1.f : 1.f;
    float qr = q * c + sg * qp * sn;
    float kr = k * c + sg * kp * sn;
    size_t o = (size_t)bh * Tt * 64 + (size_t)t * 64 + d;
    Q[o] = (__bf16)(qr * 0.18033688f);   // 0.125 * log2(e)
    K[o] = (__bf16)kr;
    Vl[tl][d] = v;
  }
  __syncthreads();
  for (int it = 0; it < 16; ++it) {
    int dr = it * 4 + tl0;
    Vt[(size_t)bh * 64 * Tt + (size_t)dr * Tt + t0 + d] = (__bf16)Vl[d][dr];
  }
}

// ---------------- Flash attention, swapped QK^T, k-parity split -------------
// grid: 2048 blocks x 128 thr = 2 waves = the 2 k-tile parities of one 32-row
// q-subtile. XCD-local mapping (XCD = bid%8 round-robin heuristic):
//   xcd=bid&7, i=bid>>3, bh=xcd*4+(i&3), i2=i>>2, c=i2>>3, j=i2&7,
//   qsub = c*8 + (c odd ? 7-j : j)
// -> each XCD owns 4 bh's (2MB K/V < 4MB L2); co-resident blocks per CU
// (bid spacing 256) share ONE bh and have snake-balanced qsub (sum 260/CU).
__global__ __launch_bounds__(128)
void attn_k(const __bf16* __restrict__ Q, const __bf16* __restrict__ K,
            const __bf16* __restrict__ Vt, __bf16* __restrict__ O) {
  const int bid = blockIdx.x;
  const int xcd = bid & 7;
  const int ii  = bid >> 3;
  const int bh  = xcd * 4 + (ii & 3);
  const int i2  = ii >> 2;
  const int c8  = i2 >> 3, j8 = i2 & 7;
  const int qsub = c8 * 8 + ((c8 & 1) ? 7 - j8 : j8);
  const int b = bh >> 4, h = bh & 15;
  const int tid = threadIdx.x, lane = tid & 63, wk = tid >> 6;
  const int l5 = lane & 31, hi = lane >> 5;
  const int qrow0 = qsub * 32;
  const size_t baseQK = (size_t)bh * Tt * 64;
  const size_t baseVt = (size_t)bh * 64 * Tt;
  const float NEG_INF = -__builtin_inff();

  __shared__ float oL[2][32][32];     // [writer wk][q-row][d-in-half]  8KB
  __shared__ float msL[2][32][2];     // [wk][q-row][(m,ssum)]

  // Q as B-operand: col q = l5, contraction d = cc*16 + hi*8 + elem
  bf16x8 qf[4];
#pragma unroll
  for (int cc = 0; cc < 4; cc++)
    qf[cc] = *(const bf16x8*)(Q + baseQK + (size_t)(qrow0 + l5) * 64 + cc * 16 + hi * 8);

  f32x16 o0 = {}, o1 = {};
  float m = NEG_INF, ssum = 0.f;

  const __bf16* Kbase = K  + baseQK + (size_t)l5 * 64 + hi * 8;
  const __bf16* Vbase = Vt + baseVt + (size_t)l5 * Tt + hi * 8;

  const int NT = qsub + 1;                 // causal 32-key tiles
  const int n  = (NT + 1 - wk) >> 1;       // tiles with parity wk

  bf16x8 kA[4], kB[4], vc[4];

#define LOADK(KA, KT) do {                                                \
    const __bf16* Kp = Kbase + (size_t)(KT) * 64;                         \
    KA[0] = *(const bf16x8*)(Kp);      KA[1] = *(const bf16x8*)(Kp + 16); \
    KA[2] = *(const bf16x8*)(Kp + 32); KA[3] = *(const bf16x8*)(Kp + 48); \
  } while (0)
#define LOADV(KT) do {                                                    \
    const __bf16* Vp = Vbase + (KT);                                      \
    vc[0] = *(const bf16x8*)(Vp);                                         \
    vc[1] = *(const bf16x8*)(Vp + 16);                                    \
    vc[2] = *(const bf16x8*)(Vp + (size_t)32 * Tt);                       \
    vc[3] = *(const bf16x8*)(Vp + (size_t)32 * Tt + 16);                  \
  } while (0)

#define COMPUTE(KA, KT0) do {                                             \
    f32x16 s = {};                                                        \
    __builtin_amdgcn_s_setprio(1);                                        \
    s = __builtin_amdgcn_mfma_f32_32x32x16_bf16(KA[0], qf[0], s, 0, 0, 0);\
    s = __builtin_amdgcn_mfma_f32_32x32x16_bf16(KA[1], qf[1], s, 0, 0, 0);\
    s = __builtin_amdgcn_mfma_f32_32x32x16_bf16(KA[2], qf[2], s, 0, 0, 0);\
    s = __builtin_amdgcn_mfma_f32_32x32x16_bf16(KA[3], qf[3], s, 0, 0, 0);\
    __builtin_amdgcn_s_setprio(0);                                        \
    float sv[16];                                                         \
    if ((KT0) == qrow0) {                                                 \
      _Pragma("unroll")                                                   \
      for (int r = 0; r < 16; r++) {                                      \
        int kof = (r & 3) + 8 * (r >> 2) + 4 * hi;                        \
        sv[r] = (kof <= l5) ? s[r] : NEG_INF;                             \
      }                                                                   \
    } else {                                                              \
      _Pragma("unroll")                                                   \
      for (int r = 0; r < 16; r++) sv[r] = s[r];                          \
    }                                                                     \
    float pmax = sv[0];                                                   \
    _Pragma("unroll")                                                     \
    for (int r = 1; r < 16; r++) pmax = fmaxf(pmax, sv[r]);               \
    pmax = xmax32(pmax);                                                  \
    if (__any(pmax > m + 11.5f)) {                                        \
      float mn = fmaxf(m, pmax);                                          \
      float al = exp2_hw(m - mn);                                         \
      m = mn;                                                             \
      ssum *= al;                                                         \
      float arow[16];                                                     \
      _Pragma("unroll")                                                   \
      for (int r = 0; r < 16; r++)                                        \
        arow[r] = __shfl(al, (r & 3) + 8 * (r >> 2) + 4 * hi);            \
      _Pragma("unroll")                                                   \
      for (int r = 0; r < 16; r++) { o0[r] *= arow[r]; o1[r] *= arow[r]; }\
    }                                                                     \
    float p[16], rsl = 0.f;                                               \
    _Pragma("unroll")                                                     \
    for (int r = 0; r < 16; r++) { p[r] = exp2_hw(sv[r] - m); rsl += p[r]; } \
    ssum += xsum32(rsl);                                                  \
    bf16x8 pa[2];                                                         \
    _Pragma("unroll")                                                     \
    for (int kc = 0; kc < 2; kc++) {                                      \
      const float* pp = p + kc * 8;                                       \
      unsigned X0 = cvtpk_bf16(pp[0], pp[1]);                             \
      unsigned Y0 = cvtpk_bf16(pp[4], pp[5]);                             \
      unsigned X1 = cvtpk_bf16(pp[2], pp[3]);                             \
      unsigned Y1 = cvtpk_bf16(pp[6], pp[7]);                             \
      u32x2 q0 = __builtin_amdgcn_permlane32_swap(X0, Y0, false, false);  \
      u32x2 q1 = __builtin_amdgcn_permlane32_swap(X1, Y1, false, false);  \
      u32x4 pw;                                                           \
      pw[0] = q0[0]; pw[1] = q1[0]; pw[2] = q0[1]; pw[3] = q1[1];         \
      pa[kc] = __builtin_bit_cast(bf16x8, pw);                            \
    }                                                                     \
    __builtin_amdgcn_s_setprio(1);                                        \
    o0 = __builtin_amdgcn_mfma_f32_32x32x16_bf16(pa[0], vc[0], o0, 0, 0, 0);\
    o0 = __builtin_amdgcn_mfma_f32_32x32x16_bf16(pa[1], vc[1], o0, 0, 0, 0);\
    o1 = __builtin_amdgcn_mfma_f32_32x32x16_bf16(pa[0], vc[2], o1, 0, 0, 0);\
    o1 = __builtin_amdgcn_mfma_f32_32x32x16_bf16(pa[1], vc[3], o1, 0, 0, 0);\
    __builtin_amdgcn_s_setprio(0);                                        \
  } while (0)

  // clamped tile start (harmless re-read of diagonal tile when overshooting)
#define KTC(idx) ( ((idx) * 32 > qrow0) ? qrow0 : (idx) * 32 )

  LOADK(kA, KTC(wk));
  int i = 0;
  for (; i + 2 <= n; i += 2) {
    LOADV((wk + 2 * i) * 32);
    LOADK(kB, KTC(wk + 2 * i + 2));
    COMPUTE(kA, (wk + 2 * i) * 32);
    LOADV((wk + 2 * i + 2) * 32);
    LOADK(kA, KTC(wk + 2 * i + 4));
    COMPUTE(kB, (wk + 2 * i + 2) * 32);
  }
  if (i < n) {
    LOADV((wk + 2 * i) * 32);
    COMPUTE(kA, (wk + 2 * i) * 32);
  }

  // ---- flash-decoding combine across the two k-parities ----
  // wave wk keeps d-half wk; writes the OTHER half to LDS for its partner.
  if (wk == 0) {
#pragma unroll
    for (int r = 0; r < 16; r++) {
      int row = (r & 3) + 8 * (r >> 2) + 4 * hi;
      oL[0][row][l5] = o1[r];
    }
  } else {
#pragma unroll
    for (int r = 0; r < 16; r++) {
      int row = (r & 3) + 8 * (r >> 2) + 4 * hi;
      oL[1][row][l5] = o0[r];
    }
  }
  if (hi == 0) { msL[wk][l5][0] = m; msL[wk][l5][1] = ssum; }
  __syncthreads();

#pragma unroll
  for (int r = 0; r < 16; r++) {
    int row = (r & 3) + 8 * (r >> 2) + 4 * hi;
    float2 mo = *(const float2*)&msL[wk][row][0];
    float2 mp = *(const float2*)&msL[wk ^ 1][row][0];
    float mM = fmaxf(mo.x, mp.x);
    float aO = exp2_hw(mo.x - mM);
    float aP = exp2_hw(mp.x - mM);
    float inv = 1.f / (aO * mo.y + aP * mp.y);
    float op  = oL[wk ^ 1][row][l5];
    float own = wk ? o1[r] : o0[r];
    float val = (aO * own + aP * op) * inv;
    int qg2 = qrow0 + row;
    O[((size_t)b * Tt + qg2) * DMm + h * 64 + wk * 32 + l5] = (__bf16)val;
  }
}

// ---------------- launch -----------------------------------------------------
extern "C" void kernel_launch(void* const* d_in, const int* in_sizes, int n_in,
                              void* d_out, int out_size, void* d_ws, size_t ws_size,
                              hipStream_t stream) {
  const float* x     = (const float*)d_in[0];
  const float* cosb  = (const float*)d_in[1];
  const float* sinb  = (const float*)d_in[2];
  const float* wqkv  = (const float*)d_in[3];
  const float* wproj = (const float*)d_in[4];
  float* out = (float*)d_out;

  char* ws = (char*)d_ws;
  __bf16* xb     = (__bf16*)(ws + 0);          //  8 MB  (4096x1024)
  __bf16* wqkvb  = (__bf16*)(ws + 8388608);    //  6 MB  (3072x1024)
  __bf16* wprojb = (__bf16*)(ws + 14680064);   //  2 MB  (1024x1024)
  __bf16* qkvh   = (__bf16*)(ws + 16777216);   // 24 MB  (4096x3072 bf16)
  __bf16* Qb     = (__bf16*)(ws + 41943040);   //  8 MB  [B,H,T,64]
  __bf16* Kb     = (__bf16*)(ws + 50331648);   //  8 MB  [B,H,T,64]
  __bf16* Vtb    = (__bf16*)(ws + 58720256);   //  8 MB  [B,H,64,T]
  __bf16* attno  = (__bf16*)(ws + 67108864);   //  8 MB  [B,T,1024]

  cast_k<<<4096, 256, 0, stream>>>(x,     xb,     1048576);
  cast_k<<<3072, 256, 0, stream>>>(wqkv,  wqkvb,   786432);
  cast_k<<<1024, 256, 0, stream>>>(wproj, wprojb,  262144);

  dim3 g1(3072 / 128, Mrows / 128);
  gemm_bt_h<<<g1, 256, 0, stream>>>(xb, wqkvb, qkvh, Mrows, 3072, 1024);

  dim3 gr(Tt / 64, Bb * Hh);
  rope_k<<<gr, 256, 0, stream>>>(qkvh, cosb, sinb, Qb, Kb, Vtb);

  attn_k<<<2048, 128, 0, stream>>>(Qb, Kb, Vtb, attno);

  dim3 g2(DMm / 128, Mrows / 128);
  gemm_bt<<<g2, 256, 0, stream>>>(attno, wprojb, out, Mrows, DMm, 1024);
}

// Round 8
// 157.985 us; speedup vs baseline: 1.2568x; 1.0066x over previous
//
#include <hip/hip_runtime.h>
#include <stdint.h>

// Problem constants
#define Bb 2
#define Tt 2048
#define DMm 1024
#define Hh 16
#define HDd 64
#define Mrows (Bb*Tt)          // 4096

typedef __attribute__((ext_vector_type(8)))  __bf16 bf16x8;
typedef __attribute__((ext_vector_type(4)))  __bf16 bf16x4;
typedef __attribute__((ext_vector_type(4)))  float  f32x4;
typedef __attribute__((ext_vector_type(16))) float  f32x16;
typedef __attribute__((ext_vector_type(4)))  unsigned int u32x4;
typedef __attribute__((ext_vector_type(2)))  unsigned int u32x2;

#define GLD16(gp, lp) __builtin_amdgcn_global_load_lds( \
    (const __attribute__((address_space(1))) unsigned int*)(gp), \
    (__attribute__((address_space(3))) unsigned int*)(lp), 16, 0, 0)

static __device__ __forceinline__ unsigned cvtpk_bf16(float lo, float hi) {
  unsigned r;
  asm("v_cvt_pk_bf16_f32 %0, %1, %2" : "=v"(r) : "v"(lo), "v"(hi));
  return r;
}
static __device__ __forceinline__ float exp2_hw(float x) {
  float r;
  asm("v_exp_f32 %0, %1" : "=v"(r) : "v"(x));
  return r;
}
// cross-half reduce: validated __shfl_xor form (R3/R4).
// NOTE: permlane32_swap(u,u) with IDENTICAL operands mis-executed (R5 fail) —
// only use it with distinct values (as in the P-pack below).
static __device__ __forceinline__ float xmax32(float v) {
  return fmaxf(v, __shfl_xor(v, 32));
}
static __device__ __forceinline__ float xsum32(float v) {
  return v + __shfl_xor(v, 32);
}

// ---------------- cast fp32 -> bf16 (vectorized) ----------------
__global__ __launch_bounds__(256)
void cast_k(const float* __restrict__ in, __bf16* __restrict__ out, int n4) {
  int i = blockIdx.x * 256 + threadIdx.x;
  if (i >= n4) return;
  float4 v = ((const float4*)in)[i];
  bf16x4 o;
  o[0] = (__bf16)v.x; o[1] = (__bf16)v.y; o[2] = (__bf16)v.z; o[3] = (__bf16)v.w;
  ((bf16x4*)out)[i] = o;
}

// ---------------- GEMM: C[M][N] = A[M][K] * B[N][K]^T ----------------------
#define GEMM_BODY(CSTORE)                                                     \
  __shared__ __bf16 As[128 * 32];                                             \
  __shared__ __bf16 Bs[128 * 32];                                             \
  const int tid  = threadIdx.x;                                               \
  const int lane = tid & 63, wid = tid >> 6;                                  \
  const int l4 = lane & 15, lhi = lane >> 4;                                  \
  const int rowBase = blockIdx.y * 128, colBase = blockIdx.x * 128;           \
  const int wh = wid >> 1, ww = wid & 1;                                      \
  f32x4 acc[4][4] = {};                                                       \
  const int e0 = wid * 512 + lane * 8;                                        \
  const int r0 = e0 >> 5, c0 = e0 & 31;                                       \
  const __bf16* a0 = A  + (size_t)(rowBase + r0)      * K + c0;               \
  const __bf16* a1 = A  + (size_t)(rowBase + r0 + 64) * K + c0;               \
  const __bf16* b0 = Bm + (size_t)(colBase + r0)      * K + c0;               \
  const __bf16* b1 = Bm + (size_t)(colBase + r0 + 64) * K + c0;               \
  for (int k0 = 0; k0 < K; k0 += 32) {                                        \
    __syncthreads();                                                          \
    GLD16(a0 + k0, &As[wid * 512]);                                           \
    GLD16(a1 + k0, &As[2048 + wid * 512]);                                    \
    GLD16(b0 + k0, &Bs[wid * 512]);                                           \
    GLD16(b1 + k0, &Bs[2048 + wid * 512]);                                    \
    __syncthreads();                                                          \
    bf16x8 af[4], bfr[4];                                                     \
    _Pragma("unroll")                                                         \
    for (int i = 0; i < 4; i++) {                                             \
      af[i]  = *(const bf16x8*)&As[(wh * 64 + i * 16 + l4) * 32 + lhi * 8];   \
      bfr[i] = *(const bf16x8*)&Bs[(ww * 64 + i * 16 + l4) * 32 + lhi * 8];   \
    }                                                                         \
    _Pragma("unroll")                                                         \
    for (int i = 0; i < 4; i++)                                               \
      _Pragma("unroll")                                                       \
      for (int j = 0; j < 4; j++)                                             \
        acc[i][j] = __builtin_amdgcn_mfma_f32_16x16x32_bf16(af[i], bfr[j], acc[i][j], 0, 0, 0); \
  }                                                                           \
  _Pragma("unroll")                                                           \
  for (int i = 0; i < 4; i++) {                                               \
    int R = rowBase + wh * 64 + i * 16 + lhi * 4;                             \
    _Pragma("unroll")                                                         \
    for (int j = 0; j < 4; j++) {                                             \
      int Cc = colBase + ww * 64 + j * 16 + l4;                               \
      CSTORE;                                                                 \
    }                                                                         \
  }

__global__ __launch_bounds__(256)
void gemm_bt(const __bf16* __restrict__ A, const __bf16* __restrict__ Bm,
             float* __restrict__ C, int M, int N, int K) {
  GEMM_BODY({
    float* cp = C + (size_t)R * N + Cc;
    _Pragma("unroll")
    for (int q = 0; q < 4; q++) cp[(size_t)q * N] = acc[i][j][q];
  })
}

__global__ __launch_bounds__(256)
void gemm_bt_h(const __bf16* __restrict__ A, const __bf16* __restrict__ Bm,
               __bf16* __restrict__ C, int M, int N, int K) {
  GEMM_BODY({
    __bf16* cp = C + (size_t)R * N + Cc;
    _Pragma("unroll")
    for (int q = 0; q < 4; q++) cp[(size_t)q * N] = (__bf16)acc[i][j][q];
  })
}

// ---------------- RoPE (bf16 in) + scatter Q/K [B,H,T,64], V^T [B,H,64,T] ---
__global__ __launch_bounds__(256)
void rope_k(const __bf16* __restrict__ qkv, const float* __restrict__ cosb,
            const float* __restrict__ sinb,
            __bf16* __restrict__ Q, __bf16* __restrict__ K, __bf16* __restrict__ Vt) {
  const int bh = blockIdx.y;           // b*16 + h
  const int b = bh >> 4, h = bh & 15;
  const int t0 = blockIdx.x * 64;
  __shared__ float Vl[64][65];
  const int tid = threadIdx.x;
  const int d = tid & 63;
  const int tl0 = tid >> 6;

  for (int it = 0; it < 16; ++it) {
    int tl = it * 4 + tl0;
    int t = t0 + tl;
    const __bf16* row = qkv + (size_t)(b * Tt + t) * 3072 + h * 64;
    float q  = (float)row[d],        qp = (float)row[d ^ 32];
    float k  = (float)row[1024 + d], kp = (float)row[1024 + (d ^ 32)];
    float v  = (float)row[2048 + d];
    float c  = cosb[t * 64 + d], sn = sinb[t * 64 + d];
    float sg = (d < 32) ? -1.f : 1.f;
    float qr = q * c + sg * qp * sn;
    float kr = k * c + sg * kp * sn;
    size_t o = (size_t)bh * Tt * 64 + (size_t)t * 64 + d;
    Q[o] = (__bf16)(qr * 0.18033688f);   // 0.125 * log2(e)
    K[o] = (__bf16)kr;
    Vl[tl][d] = v;
  }
  __syncthreads();
  for (int it = 0; it < 16; ++it) {
    int dr = it * 4 + tl0;
    Vt[(size_t)bh * 64 * Tt + (size_t)dr * Tt + t0 + d] = (__bf16)Vl[d][dr];
  }
}

// ---------------- Flash attention: qsub-pair blocks, k-parity waves ---------
// grid: 1024 blocks x 256 thr = 4 waves. Block (bh, j) owns q-subtiles
// {j, 63-j}: total causal tiles (j+1)+(64-j) = 65 for EVERY block -> all
// blocks finish together (kills the R6/R7 straggler tail).
// wave wid: wq=wid>>1 selects qsub (0 -> j, 1 -> 63-j), wk=wid&1 = k-parity.
// XCD-local: xcd=bid&7 -> bh = xcd*4+(ii&3); 4 bh per XCD (2MB K/V in L2);
// co-resident blocks on a CU (bid spacing 256) share one bh.
__global__ __launch_bounds__(256)
void attn_k(const __bf16* __restrict__ Q, const __bf16* __restrict__ K,
            const __bf16* __restrict__ Vt, __bf16* __restrict__ O) {
  const int bid = blockIdx.x;
  const int xcd = bid & 7;
  const int ii  = bid >> 3;
  const int bh  = xcd * 4 + (ii & 3);
  const int jj  = ii >> 2;                  // 0..31
  const int b = bh >> 4, h = bh & 15;
  const int tid = threadIdx.x, lane = tid & 63, wid = tid >> 6;
  const int wq = wid >> 1, wk = wid & 1;
  const int qsub = wq ? (63 - jj) : jj;
  const int l5 = lane & 31, hi = lane >> 5;
  const int qrow0 = qsub * 32;
  const size_t baseQK = (size_t)bh * Tt * 64;
  const size_t baseVt = (size_t)bh * 64 * Tt;
  const float NEG_INF = -__builtin_inff();

  __shared__ float oL[2][2][32][32];  // [wq][writer wk][q-row][d-in-half] 16KB
  __shared__ float msL[2][2][32][2];  // [wq][wk][q-row][(m,ssum)]

  // Q as B-operand: col q = l5, contraction d = cc*16 + hi*8 + elem
  bf16x8 qf[4];
#pragma unroll
  for (int cc = 0; cc < 4; cc++)
    qf[cc] = *(const bf16x8*)(Q + baseQK + (size_t)(qrow0 + l5) * 64 + cc * 16 + hi * 8);

  f32x16 o0 = {}, o1 = {};
  float m = NEG_INF, ssum = 0.f;

  const __bf16* Kbase = K  + baseQK + (size_t)l5 * 64 + hi * 8;
  const __bf16* Vbase = Vt + baseVt + (size_t)l5 * Tt + hi * 8;

  const int NT = qsub + 1;                 // causal 32-key tiles
  const int n  = (NT + 1 - wk) >> 1;       // tiles with parity wk

  bf16x8 kA[4], kB[4], vc[4];

#define LOADK(KA, KT) do {                                                \
    const __bf16* Kp = Kbase + (size_t)(KT) * 64;                         \
    KA[0] = *(const bf16x8*)(Kp);      KA[1] = *(const bf16x8*)(Kp + 16); \
    KA[2] = *(const bf16x8*)(Kp + 32); KA[3] = *(const bf16x8*)(Kp + 48); \
  } while (0)
#define LOADV(KT) do {                                                    \
    const __bf16* Vp = Vbase + (KT);                                      \
    vc[0] = *(const bf16x8*)(Vp);                                         \
    vc[1] = *(const bf16x8*)(Vp + 16);                                    \
    vc[2] = *(const bf16x8*)(Vp + (size_t)32 * Tt);                       \
    vc[3] = *(const bf16x8*)(Vp + (size_t)32 * Tt + 16);                  \
  } while (0)

#define COMPUTE(KA, KT0) do {                                             \
    f32x16 s = {};                                                        \
    __builtin_amdgcn_s_setprio(1);                                        \
    s = __builtin_amdgcn_mfma_f32_32x32x16_bf16(KA[0], qf[0], s, 0, 0, 0);\
    s = __builtin_amdgcn_mfma_f32_32x32x16_bf16(KA[1], qf[1], s, 0, 0, 0);\
    s = __builtin_amdgcn_mfma_f32_32x32x16_bf16(KA[2], qf[2], s, 0, 0, 0);\
    s = __builtin_amdgcn_mfma_f32_32x32x16_bf16(KA[3], qf[3], s, 0, 0, 0);\
    __builtin_amdgcn_s_setprio(0);                                        \
    float sv[16];                                                         \
    if ((KT0) == qrow0) {                                                 \
      _Pragma("unroll")                                                   \
      for (int r = 0; r < 16; r++) {                                      \
        int kof = (r & 3) + 8 * (r >> 2) + 4 * hi;                        \
        sv[r] = (kof <= l5) ? s[r] : NEG_INF;                             \
      }                                                                   \
    } else {                                                              \
      _Pragma("unroll")                                                   \
      for (int r = 0; r < 16; r++) sv[r] = s[r];                          \
    }                                                                     \
    float pmax = sv[0];                                                   \
    _Pragma("unroll")                                                     \
    for (int r = 1; r < 16; r++) pmax = fmaxf(pmax, sv[r]);               \
    pmax = xmax32(pmax);                                                  \
    if (__any(pmax > m + 11.5f)) {                                        \
      float mn = fmaxf(m, pmax);                                          \
      float al = exp2_hw(m - mn);                                         \
      m = mn;                                                             \
      ssum *= al;                                                         \
      float arow[16];                                                     \
      _Pragma("unroll")                                                   \
      for (int r = 0; r < 16; r++)                                        \
        arow[r] = __shfl(al, (r & 3) + 8 * (r >> 2) + 4 * hi);            \
      _Pragma("unroll")                                                   \
      for (int r = 0; r < 16; r++) { o0[r] *= arow[r]; o1[r] *= arow[r]; }\
    }                                                                     \
    float p[16], rsl = 0.f;                                               \
    _Pragma("unroll")                                                     \
    for (int r = 0; r < 16; r++) { p[r] = exp2_hw(sv[r] - m); rsl += p[r]; } \
    ssum += xsum32(rsl);                                                  \
    bf16x8 pa[2];                                                         \
    _Pragma("unroll")                                                     \
    for (int kc = 0; kc < 2; kc++) {                                      \
      const float* pp = p + kc * 8;                                       \
      unsigned X0 = cvtpk_bf16(pp[0], pp[1]);                             \
      unsigned Y0 = cvtpk_bf16(pp[4], pp[5]);                             \
      unsigned X1 = cvtpk_bf16(pp[2], pp[3]);                             \
      unsigned Y1 = cvtpk_bf16(pp[6], pp[7]);                             \
      u32x2 q0 = __builtin_amdgcn_permlane32_swap(X0, Y0, false, false);  \
      u32x2 q1 = __builtin_amdgcn_permlane32_swap(X1, Y1, false, false);  \
      u32x4 pw;                                                           \
      pw[0] = q0[0]; pw[1] = q1[0]; pw[2] = q0[1]; pw[3] = q1[1];         \
      pa[kc] = __builtin_bit_cast(bf16x8, pw);                            \
    }                                                                     \
    __builtin_amdgcn_s_setprio(1);                                        \
    o0 = __builtin_amdgcn_mfma_f32_32x32x16_bf16(pa[0], vc[0], o0, 0, 0, 0);\
    o0 = __builtin_amdgcn_mfma_f32_32x32x16_bf16(pa[1], vc[1], o0, 0, 0, 0);\
    o1 = __builtin_amdgcn_mfma_f32_32x32x16_bf16(pa[0], vc[2], o1, 0, 0, 0);\
    o1 = __builtin_amdgcn_mfma_f32_32x32x16_bf16(pa[1], vc[3], o1, 0, 0, 0);\
    __builtin_amdgcn_s_setprio(0);                                        \
  } while (0)

  // clamped tile start (harmless re-read of diagonal tile when overshooting)
#define KTC(idx) ( ((idx) * 32 > qrow0) ? qrow0 : (idx) * 32 )

  LOADK(kA, KTC(wk));
  int i = 0;
  for (; i + 2 <= n; i += 2) {
    LOADV((wk + 2 * i) * 32);
    LOADK(kB, KTC(wk + 2 * i + 2));
    COMPUTE(kA, (wk + 2 * i) * 32);
    LOADV((wk + 2 * i + 2) * 32);
    LOADK(kA, KTC(wk + 2 * i + 4));
    COMPUTE(kB, (wk + 2 * i + 2) * 32);
  }
  if (i < n) {
    LOADV((wk + 2 * i) * 32);
    COMPUTE(kA, (wk + 2 * i) * 32);
  }

  // ---- flash-decoding combine across the two k-parities (per wq) ----
  // wave wk keeps d-half wk; writes the OTHER half to LDS for its partner.
  if (wk == 0) {
#pragma unroll
    for (int r = 0; r < 16; r++) {
      int row = (r & 3) + 8 * (r >> 2) + 4 * hi;
      oL[wq][0][row][l5] = o1[r];
    }
  } else {
#pragma unroll
    for (int r = 0; r < 16; r++) {
      int row = (r & 3) + 8 * (r >> 2) + 4 * hi;
      oL[wq][1][row][l5] = o0[r];
    }
  }
  if (hi == 0) { msL[wq][wk][l5][0] = m; msL[wq][wk][l5][1] = ssum; }
  __syncthreads();

#pragma unroll
  for (int r = 0; r < 16; r++) {
    int row = (r & 3) + 8 * (r >> 2) + 4 * hi;
    float2 mo = *(const float2*)&msL[wq][wk][row][0];
    float2 mp = *(const float2*)&msL[wq][wk ^ 1][row][0];
    float mM = fmaxf(mo.x, mp.x);
    float aO = exp2_hw(mo.x - mM);
    float aP = exp2_hw(mp.x - mM);
    float inv = 1.f / (aO * mo.y + aP * mp.y);
    float op  = oL[wq][wk ^ 1][row][l5];
    float own = wk ? o1[r] : o0[r];
    float val = (aO * own + aP * op) * inv;
    int qg2 = qrow0 + row;
    O[((size_t)b * Tt + qg2) * DMm + h * 64 + wk * 32 + l5] = (__bf16)val;
  }
}

// ---------------- launch -----------------------------------------------------
extern "C" void kernel_launch(void* const* d_in, const int* in_sizes, int n_in,
                              void* d_out, int out_size, void* d_ws, size_t ws_size,
                              hipStream_t stream) {
  const float* x     = (const float*)d_in[0];
  const float* cosb  = (const float*)d_in[1];
  const float* sinb  = (const float*)d_in[2];
  const float* wqkv  = (const float*)d_in[3];
  const float* wproj = (const float*)d_in[4];
  float* out = (float*)d_out;

  char* ws = (char*)d_ws;
  __bf16* xb     = (__bf16*)(ws + 0);          //  8 MB  (4096x1024)
  __bf16* wqkvb  = (__bf16*)(ws + 8388608);    //  6 MB  (3072x1024)
  __bf16* wprojb = (__bf16*)(ws + 14680064);   //  2 MB  (1024x1024)
  __bf16* qkvh   = (__bf16*)(ws + 16777216);   // 24 MB  (4096x3072 bf16)
  __bf16* Qb     = (__bf16*)(ws + 41943040);   //  8 MB  [B,H,T,64]
  __bf16* Kb     = (__bf16*)(ws + 50331648);   //  8 MB  [B,H,T,64]
  __bf16* Vtb    = (__bf16*)(ws + 58720256);   //  8 MB  [B,H,64,T]
  __bf16* attno  = (__bf16*)(ws + 67108864);   //  8 MB  [B,T,1024]

  cast_k<<<4096, 256, 0, stream>>>(x,     xb,     1048576);
  cast_k<<<3072, 256, 0, stream>>>(wqkv,  wqkvb,   786432);
  cast_k<<<1024, 256, 0, stream>>>(wproj, wprojb,  262144);

  dim3 g1(3072 / 128, Mrows / 128);
  gemm_bt_h<<<g1, 256, 0, stream>>>(xb, wqkvb, qkvh, Mrows, 3072, 1024);

  dim3 gr(Tt / 64, Bb * Hh);
  rope_k<<<gr, 256, 0, stream>>>(qkvh, cosb, sinb, Qb, Kb, Vtb);

  attn_k<<<1024, 256, 0, stream>>>(Qb, Kb, Vtb, attno);

  dim3 g2(DMm / 128, Mrows / 128);
  gemm_bt<<<g2, 256, 0, stream>>>(attno, wprojb, out, Mrows, DMm, 1024);
}